// Round 12
// baseline (331.467 us; speedup 1.0000x reference)
//
#include <hip/hip_runtime.h>
#include <hip/hip_bf16.h>

#define S_LEN  2048
#define DMODEL 2048
#define NH     32
#define NG     8
#define DK     64
#define DV     64

typedef short bf16x8 __attribute__((ext_vector_type(8)));
typedef float f32x4  __attribute__((ext_vector_type(4)));

__device__ __forceinline__ ushort f32_to_bf16(float f) {
    uint u = __float_as_uint(f);
    return (ushort)((u + 0x7fffu + ((u >> 16) & 1u)) >> 16);   // RNE
}
__device__ __forceinline__ float bf16_to_f32(ushort h) {
    return __uint_as_float(((uint)h) << 16);
}
__device__ __forceinline__ uint pack_bf16x2(float a, float b) {
    return (uint)f32_to_bf16(a) | ((uint)f32_to_bf16(b) << 16);
}
// HW packed cast: D = {bf16(a) | bf16(b)<<16}, RNE (no builtin on gfx950; m240)
__device__ __forceinline__ uint cvtpk(float a, float b) {
    uint r;
    asm("v_cvt_pk_bf16_f32 %0, %1, %2" : "=v"(r) : "v"(a), "v"(b));
    return r;
}

// ---------------------- fused W[K][N] f32 -> Wt[N][K] bf16 for all four weights
// grid.x block ranges: [0,64) Wq, [64,80) Wk, [80,96) Wv, [96,160) Wo. K=2048.
__global__ void transpose_cast4(const float* __restrict__ Wq,
                                const float* __restrict__ Wk,
                                const float* __restrict__ Wv,
                                const float* __restrict__ Wo,
                                ushort* __restrict__ Wqt, ushort* __restrict__ Wkt,
                                ushort* __restrict__ Wvt, ushort* __restrict__ Wot) {
    __shared__ float t[32][33];
    int bx = blockIdx.x;
    const float* W; ushort* Wt; int N;
    if (bx < 64)      { W = Wq; Wt = Wqt; N = 2048; }
    else if (bx < 80) { W = Wk; Wt = Wkt; N = 512;  bx -= 64; }
    else if (bx < 96) { W = Wv; Wt = Wvt; N = 512;  bx -= 80; }
    else              { W = Wo; Wt = Wot; N = 2048; bx -= 96; }
    const int n0 = bx * 32, k0 = blockIdx.y * 32;
    const int tx = threadIdx.x, ty = threadIdx.y;   // 32 x 8
#pragma unroll
    for (int i = 0; i < 4; ++i)
        t[ty + 8 * i][tx] = W[(size_t)(k0 + ty + 8 * i) * N + n0 + tx];
    __syncthreads();
#pragma unroll
    for (int i = 0; i < 4; ++i)
        Wt[(size_t)(n0 + ty + 8 * i) * 2048 + k0 + tx] = f32_to_bf16(t[tx][ty + 8 * i]);
}

// ------------------------------------------------------------- bf16 MFMA GEMM
// C[M][N] = (A[M][K] @ Bt[N][K]^T + bias) * scale.  128(M)x64(N) tile, 4 waves
// stacked in M (each: 32 rows x 64 cols = 2x4 frags of mfma_f32_16x16x32_bf16).
// BK=64, LDS row stride 72 shorts (144B -> 2-way alias only).  Depth-2
// register prefetch (named sets X/Y).  Requires K % 128 == 0.
// AF32: A is f32 in HBM; cast to bf16 (RNE, v_cvt_pk_bf16_f32) during LDS
// staging — removes the standalone cast kernel's read+write round trip.
// MODE: 0 = bf16 C, 1 = f32 C, 2 = bf16 C^T (V^T, output stride S_LEN) via LDS.
template <int MODE, bool AF32>
__device__ __forceinline__ void gemm_body_128x64(
        const void* __restrict__ Av, const ushort* __restrict__ Bt,
        const float* __restrict__ bias, void* __restrict__ Cv,
        ushort* As, ushort* Bs, ushort* Ts, int N, int K, float scale,
        int bx, int by) {
    const int tid  = threadIdx.x;
    const int lane = tid & 63, wave = tid >> 6;
    const int l15 = lane & 15, quad = lane >> 4;
    const int row0 = by * 128, col0 = bx * 64;

    f32x4 acc[2][4];
#pragma unroll
    for (int i = 0; i < 2; ++i)
#pragma unroll
        for (int j = 0; j < 4; ++j) { f32x4 z = {0.f,0.f,0.f,0.f}; acc[i][j] = z; }

    // staging coords (BK=64): A 128x64 (64B/thread), B 64x64 (2 b128/thread)
    const int ar = tid >> 1, ak = (tid & 1) * 32;
    const int br = tid >> 2, bk = (tid & 3) * 16;
    const ushort* aptrh = AF32 ? nullptr
                               : (const ushort*)Av + (size_t)(row0 + ar) * K + ak;
    const float*  aptrf = AF32 ? (const float*)Av + (size_t)(row0 + ar) * K + ak
                               : nullptr;
    const ushort* bptr = Bt + (size_t)(col0 + br) * K + bk;

    // ---- depth-2 named register sets (rule #20: no runtime indexing)
    bf16x8 xh0, xh1, xh2, xh3, yh0, yh1, yh2, yh3;                 // bf16 A
    float4 xf0, xf1, xf2, xf3, xf4, xf5, xf6, xf7;                 // f32 A (X)
    float4 yf0, yf1, yf2, yf3, yf4, yf5, yf6, yf7;                 // f32 A (Y)
    bf16x8 xb0, xb1, yb0, yb1;                                     // B

    if (AF32) {
        xf0 = *(const float4*)(aptrf);      xf1 = *(const float4*)(aptrf + 4);
        xf2 = *(const float4*)(aptrf + 8);  xf3 = *(const float4*)(aptrf + 12);
        xf4 = *(const float4*)(aptrf + 16); xf5 = *(const float4*)(aptrf + 20);
        xf6 = *(const float4*)(aptrf + 24); xf7 = *(const float4*)(aptrf + 28);
        yf0 = *(const float4*)(aptrf + 64); yf1 = *(const float4*)(aptrf + 68);
        yf2 = *(const float4*)(aptrf + 72); yf3 = *(const float4*)(aptrf + 76);
        yf4 = *(const float4*)(aptrf + 80); yf5 = *(const float4*)(aptrf + 84);
        yf6 = *(const float4*)(aptrf + 88); yf7 = *(const float4*)(aptrf + 92);
    } else {
        xh0 = *(const bf16x8*)(aptrh);      xh1 = *(const bf16x8*)(aptrh + 8);
        xh2 = *(const bf16x8*)(aptrh + 16); xh3 = *(const bf16x8*)(aptrh + 24);
        yh0 = *(const bf16x8*)(aptrh + 64); yh1 = *(const bf16x8*)(aptrh + 72);
        yh2 = *(const bf16x8*)(aptrh + 80); yh3 = *(const bf16x8*)(aptrh + 88);
    }
    xb0 = *(const bf16x8*)(bptr);      xb1 = *(const bf16x8*)(bptr + 8);
    yb0 = *(const bf16x8*)(bptr + 64); yb1 = *(const bf16x8*)(bptr + 72);

    for (int k0 = 0; k0 < K; k0 += 128) {
        // ---------------- sub-step 0: tile k0 (set X)
        __syncthreads();
        if (AF32) {
            uint4 w;
            w.x = cvtpk(xf0.x, xf0.y); w.y = cvtpk(xf0.z, xf0.w);
            w.z = cvtpk(xf1.x, xf1.y); w.w = cvtpk(xf1.z, xf1.w);
            *(uint4*)&As[ar * 72 + ak] = w;
            w.x = cvtpk(xf2.x, xf2.y); w.y = cvtpk(xf2.z, xf2.w);
            w.z = cvtpk(xf3.x, xf3.y); w.w = cvtpk(xf3.z, xf3.w);
            *(uint4*)&As[ar * 72 + ak + 8] = w;
            w.x = cvtpk(xf4.x, xf4.y); w.y = cvtpk(xf4.z, xf4.w);
            w.z = cvtpk(xf5.x, xf5.y); w.w = cvtpk(xf5.z, xf5.w);
            *(uint4*)&As[ar * 72 + ak + 16] = w;
            w.x = cvtpk(xf6.x, xf6.y); w.y = cvtpk(xf6.z, xf6.w);
            w.z = cvtpk(xf7.x, xf7.y); w.w = cvtpk(xf7.z, xf7.w);
            *(uint4*)&As[ar * 72 + ak + 24] = w;
        } else {
            *(bf16x8*)&As[ar * 72 + ak]      = xh0;
            *(bf16x8*)&As[ar * 72 + ak + 8]  = xh1;
            *(bf16x8*)&As[ar * 72 + ak + 16] = xh2;
            *(bf16x8*)&As[ar * 72 + ak + 24] = xh3;
        }
        *(bf16x8*)&Bs[br * 72 + bk]     = xb0;
        *(bf16x8*)&Bs[br * 72 + bk + 8] = xb1;
        __syncthreads();
        if (k0 + 128 < K) {                       // X <- tile k0+128
            if (AF32) {
                const float* p = aptrf + k0 + 128;
                xf0 = *(const float4*)(p);      xf1 = *(const float4*)(p + 4);
                xf2 = *(const float4*)(p + 8);  xf3 = *(const float4*)(p + 12);
                xf4 = *(const float4*)(p + 16); xf5 = *(const float4*)(p + 20);
                xf6 = *(const float4*)(p + 24); xf7 = *(const float4*)(p + 28);
            } else {
                xh0 = *(const bf16x8*)(aptrh + k0 + 128);
                xh1 = *(const bf16x8*)(aptrh + k0 + 136);
                xh2 = *(const bf16x8*)(aptrh + k0 + 144);
                xh3 = *(const bf16x8*)(aptrh + k0 + 152);
            }
            xb0 = *(const bf16x8*)(bptr + k0 + 128);
            xb1 = *(const bf16x8*)(bptr + k0 + 136);
        }
#pragma unroll
        for (int kk = 0; kk < 2; ++kk) {
            bf16x8 af[2], bf[4];
#pragma unroll
            for (int mi = 0; mi < 2; ++mi)
                af[mi] = *(const bf16x8*)&As[(wave * 32 + mi * 16 + l15) * 72 + kk * 32 + quad * 8];
#pragma unroll
            for (int ni = 0; ni < 4; ++ni)
                bf[ni] = *(const bf16x8*)&Bs[(ni * 16 + l15) * 72 + kk * 32 + quad * 8];
#pragma unroll
            for (int mi = 0; mi < 2; ++mi)
#pragma unroll
                for (int ni = 0; ni < 4; ++ni)
                    acc[mi][ni] = __builtin_amdgcn_mfma_f32_16x16x32_bf16(
                        af[mi], bf[ni], acc[mi][ni], 0, 0, 0);
        }

        // ---------------- sub-step 1: tile k0+64 (set Y)
        __syncthreads();
        if (AF32) {
            uint4 w;
            w.x = cvtpk(yf0.x, yf0.y); w.y = cvtpk(yf0.z, yf0.w);
            w.z = cvtpk(yf1.x, yf1.y); w.w = cvtpk(yf1.z, yf1.w);
            *(uint4*)&As[ar * 72 + ak] = w;
            w.x = cvtpk(yf2.x, yf2.y); w.y = cvtpk(yf2.z, yf2.w);
            w.z = cvtpk(yf3.x, yf3.y); w.w = cvtpk(yf3.z, yf3.w);
            *(uint4*)&As[ar * 72 + ak + 8] = w;
            w.x = cvtpk(yf4.x, yf4.y); w.y = cvtpk(yf4.z, yf4.w);
            w.z = cvtpk(yf5.x, yf5.y); w.w = cvtpk(yf5.z, yf5.w);
            *(uint4*)&As[ar * 72 + ak + 16] = w;
            w.x = cvtpk(yf6.x, yf6.y); w.y = cvtpk(yf6.z, yf6.w);
            w.z = cvtpk(yf7.x, yf7.y); w.w = cvtpk(yf7.z, yf7.w);
            *(uint4*)&As[ar * 72 + ak + 24] = w;
        } else {
            *(bf16x8*)&As[ar * 72 + ak]      = yh0;
            *(bf16x8*)&As[ar * 72 + ak + 8]  = yh1;
            *(bf16x8*)&As[ar * 72 + ak + 16] = yh2;
            *(bf16x8*)&As[ar * 72 + ak + 24] = yh3;
        }
        *(bf16x8*)&Bs[br * 72 + bk]     = yb0;
        *(bf16x8*)&Bs[br * 72 + bk + 8] = yb1;
        __syncthreads();
        if (k0 + 192 < K) {                       // Y <- tile k0+192
            if (AF32) {
                const float* p = aptrf + k0 + 192;
                yf0 = *(const float4*)(p);      yf1 = *(const float4*)(p + 4);
                yf2 = *(const float4*)(p + 8);  yf3 = *(const float4*)(p + 12);
                yf4 = *(const float4*)(p + 16); yf5 = *(const float4*)(p + 20);
                yf6 = *(const float4*)(p + 24); yf7 = *(const float4*)(p + 28);
            } else {
                yh0 = *(const bf16x8*)(aptrh + k0 + 192);
                yh1 = *(const bf16x8*)(aptrh + k0 + 200);
                yh2 = *(const bf16x8*)(aptrh + k0 + 208);
                yh3 = *(const bf16x8*)(aptrh + k0 + 216);
            }
            yb0 = *(const bf16x8*)(bptr + k0 + 192);
            yb1 = *(const bf16x8*)(bptr + k0 + 200);
        }
#pragma unroll
        for (int kk = 0; kk < 2; ++kk) {
            bf16x8 af[2], bf[4];
#pragma unroll
            for (int mi = 0; mi < 2; ++mi)
                af[mi] = *(const bf16x8*)&As[(wave * 32 + mi * 16 + l15) * 72 + kk * 32 + quad * 8];
#pragma unroll
            for (int ni = 0; ni < 4; ++ni)
                bf[ni] = *(const bf16x8*)&Bs[(ni * 16 + l15) * 72 + kk * 32 + quad * 8];
#pragma unroll
            for (int mi = 0; mi < 2; ++mi)
#pragma unroll
                for (int ni = 0; ni < 4; ++ni)
                    acc[mi][ni] = __builtin_amdgcn_mfma_f32_16x16x32_bf16(
                        af[mi], bf[ni], acc[mi][ni], 0, 0, 0);
        }
    }

    if (MODE == 2) {
        // ---- V^T epilogue: stage 128(s) x 64(v) accs into LDS as [v][s],
        // then coalesced store to Cv[v][s] with row stride S_LEN.
        __syncthreads();                  // last K-step's LDS reads done
#pragma unroll
        for (int mi = 0; mi < 2; ++mi)
#pragma unroll
            for (int ni = 0; ni < 4; ++ni) {
                const float bv = bias[col0 + ni * 16 + l15];
                const int lrow = wave * 32 + mi * 16 + quad * 4;   // mult of 4
                uint2 uu;
                uu.x = pack_bf16x2((acc[mi][ni][0] + bv) * scale,
                                   (acc[mi][ni][1] + bv) * scale);
                uu.y = pack_bf16x2((acc[mi][ni][2] + bv) * scale,
                                   (acc[mi][ni][3] + bv) * scale);
                *(uint2*)&Ts[(ni * 16 + l15) * 136 + lrow] = uu;
            }
        __syncthreads();
        const int v = tid >> 2, s0 = (tid & 3) * 32;
#pragma unroll
        for (int i = 0; i < 4; ++i) {
            const uint4 d = *(const uint4*)&Ts[v * 136 + s0 + 8 * i];
            *(uint4*)&((ushort*)Cv)[(size_t)(col0 + v) * S_LEN + row0 + s0 + 8 * i] = d;
        }
        return;
    }

#pragma unroll
    for (int mi = 0; mi < 2; ++mi)
#pragma unroll
        for (int ni = 0; ni < 4; ++ni) {
            const int col = col0 + ni * 16 + l15;
            const float bv = bias[col];
#pragma unroll
            for (int reg = 0; reg < 4; ++reg) {
                const int row = row0 + wave * 32 + mi * 16 + quad * 4 + reg;
                const float val = (acc[mi][ni][reg] + bv) * scale;
                if (MODE == 1)
                    ((float*)Cv)[(size_t)row * N + col] = val;
                else
                    ((ushort*)Cv)[(size_t)row * N + col] = f32_to_bf16(val);
            }
        }
}

// XCD-aware 2D-chunk decode for 512-block GEMMs (32 col-tiles x 16 row-tiles).
__device__ __forceinline__ void xcd_decode_32x16(int d, int& bx, int& by) {
    const int xcd = d & 7, i = d >> 3;          // i in [0,64)
    bx = (xcd & 3) * 8 + (i & 7);
    by = (xcd >> 2) * 8 + (i >> 3);
}

// Q projection: queries f32 [2048,2048] x Wqt, bf16 out, scale folded
__global__ __launch_bounds__(256) void gemm_q(
        const float* __restrict__ A, const ushort* __restrict__ Bt,
        const float* __restrict__ bias, ushort* __restrict__ Cv, int K,
        float scale) {
    __shared__ ushort smem[128 * 72 + 64 * 72];
    int bx, by; xcd_decode_32x16(blockIdx.x, bx, by);
    gemm_body_128x64<0, true>(A, Bt, bias, Cv, smem, smem + 128 * 72, nullptr,
                              2048, K, scale, bx, by);
}

// O projection: Ab bf16 -> f32 out
__global__ __launch_bounds__(256) void gemm_o(
        const ushort* __restrict__ A, const ushort* __restrict__ Bt,
        const float* __restrict__ bias, float* __restrict__ Cv, int K) {
    __shared__ ushort smem[128 * 72 + 64 * 72];
    int bx, by; xcd_decode_32x16(blockIdx.x, bx, by);
    gemm_body_128x64<1, false>(A, Bt, bias, Cv, smem, smem + 128 * 72, nullptr,
                               2048, K, 1.0f, bx, by);
}

// K and V projections fused via gridDim.z; A = keys/values f32; V -> V^T (MODE 2).
__global__ __launch_bounds__(256) void gemm_kv(
        const float* __restrict__ Xk, const float* __restrict__ Xv,
        const ushort* __restrict__ Wkt, const ushort* __restrict__ Wvt,
        const float* __restrict__ bk, const float* __restrict__ bv,
        ushort* __restrict__ Kb, ushort* __restrict__ Vtp, int K) {
    __shared__ ushort smem[128 * 72 + 64 * 72];   // 13824 shorts; Ts needs 8704
    ushort* As = smem;
    ushort* Bs = smem + 128 * 72;
    if (blockIdx.z == 0)
        gemm_body_128x64<0, true>(Xk, Wkt, bk, Kb, As, Bs, nullptr, 512, K, 1.0f,
                                  blockIdx.x, blockIdx.y);
    else
        gemm_body_128x64<2, true>(Xv, Wvt, bv, Vtp, As, Bs, smem, 512, K, 1.0f,
                                  blockIdx.x, blockIdx.y);
}

// ------------------------------------------------------ MFMA flash attention
// Grid (32, 16, 2): x = head, y = pair index, z = sel; block handles ONE
// 64-row q-tile: qt = z ? 31-y : y.  1024 blocks, 4 blocks/CU all-resident.
// Ordering (head fastest) keeps per-CU causal load balanced (66 j-tile-units
// per stride-256 class) and gives each XCD a 4-of-8 KV-group L2 footprint.
// 4 waves/block; wave owns a 16-row Q stripe.
//
// SWAPPED-OPERAND version: S^T = mfma(K_frag, Q_frag) puts q in the C-layout
// column (l15) — each lane owns ONE q row. Online-softmax state (m, l) is a
// single scalar per lane; row max/sum = 15 in-lane ops + 2 shfl_xor (16, 32).
// P^T packs into per-wave LDS as [q][key] (8B vector stores) and reads back
// contiguously as the PV B-frag. PV computes O^T = mfma(V^T_frag, P^T_frag);
// V^T LDS tile is already in A-frag layout. Scale (1/sqrt(dk) * log2e) is
// pre-folded into Q; exp = exp2. Defer-max rescale (T13).
__global__ __launch_bounds__(256) void gqa_attn_mfma(
        const ushort* __restrict__ Qb, const ushort* __restrict__ Kb,
        const ushort* __restrict__ Vt, ushort* __restrict__ Ab) {
    __shared__ ushort Ks[64 * 72];       // [key][d]
    __shared__ ushort Vs[64 * 72];       // [d][key]
    __shared__ ushort Ps[4][16 * 72];    // per-wave P^T as [q][key]

    const int h    = blockIdx.x, g = h >> 2;
    const int tid  = threadIdx.x;
    const int lane = tid & 63, wave = tid >> 6;
    const int l15  = lane & 15, quad = lane >> 4;
    const int NT   = S_LEN / 64;         // 32 q-tiles
    const float DEFER_THR = 11.5416f;    // 8 * log2(e)

    // per-thread staging coordinates (fixed across tiles)
    const int srow = tid >> 2, sch = tid & 3;
    const ushort* kbase = Kb + (size_t)srow * (NG * DK) + g * DK + sch * 16;
    const ushort* vbase = Vt + (size_t)(g * 64 + srow) * S_LEN + sch * 16;

    const int qt = blockIdx.z ? (NT - 1 - (int)blockIdx.y) : (int)blockIdx.y;
    const int qr = qt * 64 + wave * 16;          // wave's first q row

    // Q frags (scale pre-folded at projection time), d=0..31 / 32..63
    bf16x8 qa0, qa1;
    {
        const size_t base = (size_t)(qr + l15) * (NH * DK) + (size_t)h * DK + quad * 8;
        qa0 = *(const bf16x8*)&Qb[base];
        qa1 = *(const bf16x8*)&Qb[base + 32];
    }

    f32x4 o[4];                          // O^T: lane = q (l15); rows = d
#pragma unroll
    for (int dt = 0; dt < 4; ++dt) { f32x4 z = {0.f,0.f,0.f,0.f}; o[dt] = z; }
    float m = -1e30f;                    // per-lane (per-q) running max, log2 domain
    float l = 0.f;                       // per-lane running sum

    // preload tile 0
    bf16x8 kr0 = *(const bf16x8*)(kbase);
    bf16x8 kr1 = *(const bf16x8*)(kbase + 8);
    bf16x8 vr0 = *(const bf16x8*)(vbase);
    bf16x8 vr1 = *(const bf16x8*)(vbase + 8);

    for (int jt = 0; jt <= qt; ++jt) {
        __syncthreads();                 // prior LDS reads complete
        *(bf16x8*)&Ks[srow * 72 + sch * 16]     = kr0;
        *(bf16x8*)&Ks[srow * 72 + sch * 16 + 8] = kr1;
        *(bf16x8*)&Vs[srow * 72 + sch * 16]     = vr0;
        *(bf16x8*)&Vs[srow * 72 + sch * 16 + 8] = vr1;
        __syncthreads();

        // prefetch tile jt+1 (flies during compute below)
        if (jt < qt) {
            const size_t ko = (size_t)(jt + 1) * 64 * (NG * DK);
            const size_t vo = (size_t)(jt + 1) * 64;
            kr0 = *(const bf16x8*)(kbase + ko);
            kr1 = *(const bf16x8*)(kbase + ko + 8);
            vr0 = *(const bf16x8*)(vbase + vo);
            vr1 = *(const bf16x8*)(vbase + vo + 8);
        }

        // S^T = K Q^T : C-layout col = q (l15), row = key (quad*4+r, +16*kt)
        f32x4 s[4];
#pragma unroll
        for (int kt = 0; kt < 4; ++kt) {
            const bf16x8 kb0 = *(const bf16x8*)&Ks[(kt * 16 + l15) * 72 + quad * 8];
            const bf16x8 kb1 = *(const bf16x8*)&Ks[(kt * 16 + l15) * 72 + 32 + quad * 8];
            f32x4 acc = {0.f, 0.f, 0.f, 0.f};
            acc = __builtin_amdgcn_mfma_f32_16x16x32_bf16(kb0, qa0, acc, 0, 0, 0);
            acc = __builtin_amdgcn_mfma_f32_16x16x32_bf16(kb1, qa1, acc, 0, 0, 0);
            s[kt] = acc;
        }

        // causal mask (diagonal tile only; scale already folded into Q)
        if (jt == qt) {
            const int row = wave * 16 + l15;   // q within the 64-row tile
#pragma unroll
            for (int kt = 0; kt < 4; ++kt)
#pragma unroll
                for (int r = 0; r < 4; ++r) {
                    const int key = kt * 16 + quad * 4 + r;
                    if (key > row) s[kt][r] = -1e30f;
                }
        }

        // tile max for this q row: 15 in-lane + cross-quad (xor 16, 32)
        float pmax;
        {
            const float t0 = fmaxf(fmaxf(s[0][0], s[0][1]), fmaxf(s[0][2], s[0][3]));
            const float t1 = fmaxf(fmaxf(s[1][0], s[1][1]), fmaxf(s[1][2], s[1][3]));
            const float t2 = fmaxf(fmaxf(s[2][0], s[2][1]), fmaxf(s[2][2], s[2][3]));
            const float t3 = fmaxf(fmaxf(s[3][0], s[3][1]), fmaxf(s[3][2], s[3][3]));
            pmax = fmaxf(fmaxf(t0, t1), fmaxf(t2, t3));
        }
        pmax = fmaxf(pmax, __shfl_xor(pmax, 16, 64));
        pmax = fmaxf(pmax, __shfl_xor(pmax, 32, 64));

        // defer-max: only rescale when the tile max grew past threshold
        if (!__all(pmax - m <= DEFER_THR)) {
            const float mnew  = fmaxf(m, pmax);
            const float alpha = __builtin_amdgcn_exp2f(m - mnew);
            l *= alpha;
#pragma unroll
            for (int dt = 0; dt < 4; ++dt)
#pragma unroll
                for (int r = 0; r < 4; ++r) o[dt][r] *= alpha;
            m = mnew;
        }

        float p[4][4];
#pragma unroll
        for (int kt = 0; kt < 4; ++kt)
#pragma unroll
            for (int r = 0; r < 4; ++r)
                p[kt][r] = __builtin_amdgcn_exp2f(s[kt][r] - m);

        float rsum;
        {
            const float u0 = (p[0][0] + p[0][1]) + (p[0][2] + p[0][3]);
            const float u1 = (p[1][0] + p[1][1]) + (p[1][2] + p[1][3]);
            const float u2 = (p[2][0] + p[2][1]) + (p[2][2] + p[2][3]);
            const float u3 = (p[3][0] + p[3][1]) + (p[3][2] + p[3][3]);
            rsum = (u0 + u1) + (u2 + u3);
        }
        rsum += __shfl_xor(rsum, 16, 64);
        rsum += __shfl_xor(rsum, 32, 64);
        l += rsum;

        // P^T -> per-wave LDS [q][key]: 8B vector stores, contiguous keys
        ushort* Pw = &Ps[wave][0];
#pragma unroll
        for (int kt = 0; kt < 4; ++kt) {
            uint2 uu;
            uu.x = pack_bf16x2(p[kt][0], p[kt][1]);
            uu.y = pack_bf16x2(p[kt][2], p[kt][3]);
            *(uint2*)&Pw[l15 * 72 + kt * 16 + quad * 4] = uu;
        }
        const bf16x8 pa0 = *(const bf16x8*)&Pw[l15 * 72 + quad * 8];
        const bf16x8 pa1 = *(const bf16x8*)&Pw[l15 * 72 + 32 + quad * 8];

        // O^T += V^T P^T : A = V^T tile (already [d][key] in LDS), B = P^T
#pragma unroll
        for (int dt = 0; dt < 4; ++dt) {
            const bf16x8 vb0 = *(const bf16x8*)&Vs[(dt * 16 + l15) * 72 + quad * 8];
            const bf16x8 vb1 = *(const bf16x8*)&Vs[(dt * 16 + l15) * 72 + 32 + quad * 8];
            o[dt] = __builtin_amdgcn_mfma_f32_16x16x32_bf16(vb0, pa0, o[dt], 0, 0, 0);
            o[dt] = __builtin_amdgcn_mfma_f32_16x16x32_bf16(vb1, pa1, o[dt], 0, 0, 0);
        }
    }

    // epilogue: lane holds O^T[d = dt*16 + quad*4 + r][q = l15]
    const float invl = 1.0f / l;
#pragma unroll
    for (int dt = 0; dt < 4; ++dt) {
        uint2 uu;
        uu.x = pack_bf16x2(o[dt][0] * invl, o[dt][1] * invl);
        uu.y = pack_bf16x2(o[dt][2] * invl, o[dt][3] * invl);
        *(uint2*)&Ab[(size_t)(qr + l15) * (NH * DV) + (size_t)h * DV + dt * 16 + quad * 4] = uu;
    }
}

// ---------------------------------------------------------------------------
extern "C" void kernel_launch(void* const* d_in, const int* in_sizes, int n_in,
                              void* d_out, int out_size, void* d_ws, size_t ws_size,
                              hipStream_t stream) {
    const float* queries = (const float*)d_in[0];
    const float* keys    = (const float*)d_in[1];
    const float* values  = (const float*)d_in[2];
    const float* Wq      = (const float*)d_in[3];
    const float* bq      = (const float*)d_in[4];
    const float* Wk      = (const float*)d_in[5];
    const float* bk      = (const float*)d_in[6];
    const float* Wv      = (const float*)d_in[7];
    const float* bv      = (const float*)d_in[8];
    const float* Wo      = (const float*)d_in[9];
    const float* bo      = (const float*)d_in[10];
    float* out = (float*)d_out;

    const size_t MB = 1024 * 1024;
    unsigned char* w = (unsigned char*)d_ws;
    ushort* Wqt = (ushort*)(w + 24 * MB);   // [2048][2048]
    ushort* Wkt = (ushort*)(w + 32 * MB);   // [512][2048]
    ushort* Wvt = (ushort*)(w + 34 * MB);
    ushort* Wot = (ushort*)(w + 36 * MB);   // [2048][2048]
    ushort* Qb  = (ushort*)(w + 44 * MB);   // [2048][2048]
    ushort* Kb  = (ushort*)(w + 52 * MB);   // [2048][512]
    ushort* Vtp = (ushort*)(w + 54 * MB);   // V^T [512][2048] (written directly)
    ushort* Ab  = (ushort*)(w + 56 * MB);   // [2048][2048]

    dim3 tb(32, 8);
    transpose_cast4<<<dim3(160, 64), tb, 0, stream>>>(
        Wq, Wk, Wv, Wo, Wqt, Wkt, Wvt, Wot);

    // Q projection (XCD-swizzled, f32 A cast in-staging); scale folded
    const float QSCALE = 0.125f * 1.44269504f;
    gemm_q<<<512, 256, 0, stream>>>(queries, Wqt, bq, Qb, DMODEL, QSCALE);

    // K and V projections fused (z=0: K, z=1: V -> V^T direct), f32 A
    gemm_kv<<<dim3(8, 16, 2), 256, 0, stream>>>(
        keys, values, Wkt, Wvt, bk, bv, Kb, Vtp, DMODEL);

    // attention: 1024 blocks, one q-tile each, stride-256-balanced ordering
    gqa_attn_mfma<<<dim3(32, 16, 2), 256, 0, stream>>>(Qb, Kb, Vtp, Ab);

    // O projection (XCD-swizzled): [2048,2048] @ [2048,2048] -> f32 out
    gemm_o<<<512, 256, 0, stream>>>(Ab, Wot, bo, out, DMODEL);
}